// Round 4
// baseline (293.253 us; speedup 1.0000x reference)
//
#include <hip/hip_runtime.h>
#include <hip/hip_fp16.h>

#define LDIM 2048
#define DDIM 1024
#define NB 8

typedef __attribute__((ext_vector_type(8))) _Float16 f16x8;
typedef __attribute__((ext_vector_type(4))) float f32x4;
typedef unsigned int u32;

#define MFMA16(a, b, c) __builtin_amdgcn_mfma_f32_16x16x32_f16(a, b, c, 0, 0, 0)

typedef const __attribute__((address_space(1))) u32* gas_t;
typedef __attribute__((address_space(3))) u32* las_t;

__device__ __forceinline__ void gl16(const _Float16* g, _Float16* l) {
  __builtin_amdgcn_global_load_lds((gas_t)g, (las_t)l, 16, 0, 0);
}

#define SBAR() __builtin_amdgcn_s_barrier()
#define VMCNT(n) asm volatile("s_waitcnt vmcnt(" #n ")" ::: "memory")
#define LGKM0 asm volatile("s_waitcnt lgkmcnt(0)" ::: "memory")
#define SCHED0 __builtin_amdgcn_sched_barrier(0)

// ---------------------------------------------------------------------------
// One phase of the 8-phase schedule: quadrant (MH, KS) of K-tile in buffer BB.
// [8x ds_read_b128 ; stage (2x gload_lds) ; counted vmcnt ; barrier ;
//  lgkmcnt(0) ; sched_barrier ; setprio(1) ; 16x MFMA ; setprio(0) ; barrier]
// LDS buffer layout (halves): buf BB at BB*32768; A at +0, B at +16384;
// within op: kh*8192 + row*32 + swizzled-chunk*8.
// ---------------------------------------------------------------------------
template <int MH, int KS, int BB, class FS, class FW>
__device__ __forceinline__ void phase(const _Float16* sh, int base_a, int base_b,
                                      f32x4 (&acc)[2][4][4], FS stg, FW wt) {
  f16x8 af[4], bf[4];
#pragma unroll
  for (int mr = 0; mr < 4; ++mr)
    af[mr] = *(const f16x8*)&sh[BB * 32768 + KS * 8192 + MH * 2048 + base_a + mr * 512];
#pragma unroll
  for (int nr = 0; nr < 4; ++nr)
    bf[nr] = *(const f16x8*)&sh[BB * 32768 + 16384 + KS * 8192 + base_b + nr * 512];
  stg();
  wt();
  __builtin_amdgcn_s_barrier();
  LGKM0;
  SCHED0;
  __builtin_amdgcn_s_setprio(1);
#pragma unroll
  for (int mr = 0; mr < 4; ++mr)
#pragma unroll
    for (int nr = 0; nr < 4; ++nr)
      acc[MH][mr][nr] = MFMA16(af[mr], bf[nr], acc[MH][mr][nr]);
  __builtin_amdgcn_s_setprio(0);
  SCHED0;
  __builtin_amdgcn_s_barrier();
}

// ---------------------------------------------------------------------------
// 8-phase 256x256 GEMM core, BK=64, 8 waves (2M x 4N), wave tile 128x64.
// A: 256 rows starting at Ab, K-major stride LDA. B likewise. K = NT*64.
// ---------------------------------------------------------------------------
template <int LDA, int NT>
__device__ __forceinline__ void gemm8(const _Float16* __restrict__ Ab,
                                      const _Float16* __restrict__ Bb,
                                      _Float16* sh, f32x4 (&acc)[2][4][4]) {
  const int tid = threadIdx.x;
  const int lane = tid & 63, w = tid >> 6;
  const int wm = w >> 2, wn = w & 3;
  const int l15 = lane & 15, g4 = lane >> 4;

  // frag-read addressing (swizzle depends only on l15; invariant across mh/mr)
  const int sw = (l15 >> 1) & 3;
  const int chk = (g4 ^ sw) << 3;
  const int base_a = (wm * 128 + l15) * 32 + chk;
  const int base_b = (wn * 64 + l15) * 32 + chk;

  // staging: thread covers (row = tid>>2 [+128 for 2nd issue], 16B chunk tid&3);
  // source chunk pre-swizzled (involution) so linear LDS dest + swizzled read match.
  const int srow = tid >> 2;
  const int scg = (tid & 3) ^ ((srow >> 1) & 3);
  const _Float16* gA = Ab + (size_t)srow * LDA + scg * 8;
  const _Float16* gB = Bb + (size_t)srow * LDA + scg * 8;
  _Float16* lw = sh + w * 512;  // wave-uniform LDS base (HW adds lane*16B)

  auto stgA = [&](int kt, int kh, int tb) {
    const _Float16* g = gA + (size_t)kt * 64 + kh * 32;
    _Float16* l = lw + tb * 32768 + kh * 8192;
    gl16(g, l);
    gl16(g + (size_t)128 * LDA, l + 4096);
  };
  auto stgB = [&](int kt, int kh, int tb) {
    const _Float16* g = gB + (size_t)kt * 64 + kh * 32;
    _Float16* l = lw + tb * 32768 + 16384 + kh * 8192;
    gl16(g, l);
    gl16(g + (size_t)128 * LDA, l + 4096);
  };

  // prologue: A_k0(0) B_k0(0) A_k1(0) B_k1(0) A_k0(1) B_k0(1); wait oldest 2 HTs
  stgA(0, 0, 0); stgB(0, 0, 0);
  stgA(0, 1, 0); stgB(0, 1, 0);
  stgA(1, 0, 1); stgB(1, 0, 1);
  VMCNT(8);
  SBAR();

  for (int t = 0; t + 3 < NT; t += 2) {
    // K-tile t (buf0)
    phase<0, 0, 0>(sh, base_a, base_b, acc, [&] { stgA(t + 1, 1, 1); }, [] {});
    phase<1, 0, 0>(sh, base_a, base_b, acc, [&] { stgB(t + 1, 1, 1); }, [] { VMCNT(8); });
    phase<0, 1, 0>(sh, base_a, base_b, acc, [&] { stgA(t + 2, 0, 0); }, [] {});
    phase<1, 1, 0>(sh, base_a, base_b, acc, [&] { stgB(t + 2, 0, 0); }, [] { VMCNT(8); });
    // K-tile t+1 (buf1)
    phase<0, 0, 1>(sh, base_a, base_b, acc, [&] { stgA(t + 2, 1, 0); }, [] {});
    phase<1, 0, 1>(sh, base_a, base_b, acc, [&] { stgB(t + 2, 1, 0); }, [] { VMCNT(8); });
    phase<0, 1, 1>(sh, base_a, base_b, acc, [&] { stgA(t + 3, 0, 1); }, [] {});
    phase<1, 1, 1>(sh, base_a, base_b, acc, [&] { stgB(t + 3, 0, 1); }, [] { VMCNT(8); });
  }
  // tail: K-tiles NT-2 (buf0), NT-1 (buf1)
  constexpr int T = NT - 2;
  phase<0, 0, 0>(sh, base_a, base_b, acc, [&] { stgA(T + 1, 1, 1); }, [] {});
  phase<1, 0, 0>(sh, base_a, base_b, acc, [&] { stgB(T + 1, 1, 1); }, [] { VMCNT(8); });
  phase<0, 1, 0>(sh, base_a, base_b, acc, [] {}, [] {});
  phase<1, 1, 0>(sh, base_a, base_b, acc, [] {}, [] { VMCNT(4); });
  phase<0, 0, 1>(sh, base_a, base_b, acc, [] {}, [] {});
  phase<1, 0, 1>(sh, base_a, base_b, acc, [] {}, [] { VMCNT(0); });
  phase<0, 1, 1>(sh, base_a, base_b, acc, [] {}, [] {});
  phase<1, 1, 1>(sh, base_a, base_b, acc, [] {}, [] {});
}

// ---------------------------------------------------------------------------
// k_prep: F (fp32 [2048][1024]) -> H (fp16 [2048][1024]) + HT (fp16 [1024][2048])
// ---------------------------------------------------------------------------
__global__ __launch_bounds__(256)
void k_prep(const float* __restrict__ F1, const float* __restrict__ F2,
            _Float16* __restrict__ H1, _Float16* __restrict__ H2,
            _Float16* __restrict__ H1T, _Float16* __restrict__ H2T) {
  __shared__ _Float16 sT[64][72];
  const int bid = blockIdx.x;
  const int inp = bid >> 12;
  const int rem = bid & 4095;
  const int b = rem >> 9, rt = (rem >> 4) & 31, ct = rem & 15;
  const int r0 = rt * 64, c0 = ct * 64;

  const float* F = (inp ? F2 : F1) + (size_t)b * LDIM * DDIM;
  _Float16* H = (inp ? H2 : H1) + (size_t)b * LDIM * DDIM;
  _Float16* HT = (inp ? H2T : H1T) + (size_t)b * DDIM * LDIM;

  const int t = threadIdx.x;
  const int row = t >> 2, seg = (t & 3) * 16;
  {
    const float* src = F + (size_t)(r0 + row) * DDIM + c0 + seg;
    float4 v0 = *(const float4*)(src), v1 = *(const float4*)(src + 4);
    float4 v2 = *(const float4*)(src + 8), v3 = *(const float4*)(src + 12);
    _Float16 h[16];
#pragma unroll
    for (int j = 0; j < 4; ++j) {
      h[j] = (_Float16)((&v0.x)[j]); h[4 + j] = (_Float16)((&v1.x)[j]);
      h[8 + j] = (_Float16)((&v2.x)[j]); h[12 + j] = (_Float16)((&v3.x)[j]);
    }
    _Float16* dst = H + (size_t)(r0 + row) * DDIM + c0 + seg;
#pragma unroll
    for (int j = 0; j < 16; ++j) dst[j] = h[j];
#pragma unroll
    for (int j = 0; j < 16; ++j) sT[seg + j][row] = h[j];
  }
  __syncthreads();
  {
    const int cloc = t >> 2, rseg = (t & 3) * 16;
    _Float16* dst = HT + (size_t)(c0 + cloc) * LDIM + r0 + rseg;
    *(uint4*)dst = *(const uint4*)&sT[cloc][rseg];
    *(uint4*)(dst + 8) = *(const uint4*)&sT[cloc][rseg + 8];
  }
}

// ---------------------------------------------------------------------------
// k_qk: S = H1 H2^T (256x256 tiles, K=1024). Epilogue: per-(row, 256-block)
// partial softmax stats + P_unnorm fp16.
// ---------------------------------------------------------------------------
__global__ __launch_bounds__(512, 2)
void k_qk(const _Float16* __restrict__ H1, const _Float16* __restrict__ H2,
          _Float16* __restrict__ P, float2* __restrict__ partials) {
  __shared__ _Float16 sh[65536];
  const int tid = threadIdx.x;
  const int lane = tid & 63, w = tid >> 6;
  const int wm = w >> 2, wn = w & 3;
  const int l15 = lane & 15, g4 = lane >> 4;

  const int nwg = gridDim.x;  // 512
  const int orig = blockIdx.x;
  const int idx = (orig & 7) * (nwg >> 3) + (orig >> 3);
  const int b = idx >> 6, mt = (idx >> 3) & 7, ntb = idx & 7;
  const int m0 = mt << 8, n0 = ntb << 8;

  f32x4 acc[2][4][4];
#pragma unroll
  for (int i = 0; i < 2; ++i)
#pragma unroll
    for (int j = 0; j < 4; ++j)
#pragma unroll
      for (int k = 0; k < 4; ++k) acc[i][j][k] = (f32x4){0.f, 0.f, 0.f, 0.f};

  gemm8<1024, 16>(H1 + (size_t)b * LDIM * DDIM + (size_t)m0 * DDIM,
                  H2 + (size_t)b * LDIM * DDIM + (size_t)n0 * DDIM, sh, acc);

  // ---- epilogue: block-partial softmax + P_unnorm ----
  float* sred = (float*)sh;        // [256][4] row-max per wn
  float* sredS = sred + 1024;      // [256][4] row-sum per wn
  __syncthreads();

#pragma unroll
  for (int mh = 0; mh < 2; ++mh)
#pragma unroll
    for (int mr = 0; mr < 4; ++mr)
#pragma unroll
      for (int r = 0; r < 4; ++r) {
        float v = fmaxf(fmaxf(acc[mh][mr][0][r], acc[mh][mr][1][r]),
                        fmaxf(acc[mh][mr][2][r], acc[mh][mr][3][r]));
        v = fmaxf(v, __shfl_xor(v, 1, 64));
        v = fmaxf(v, __shfl_xor(v, 2, 64));
        v = fmaxf(v, __shfl_xor(v, 4, 64));
        v = fmaxf(v, __shfl_xor(v, 8, 64));
        if (l15 == 0) sred[(wm * 128 + mh * 64 + mr * 16 + g4 * 4 + r) * 4 + wn] = v;
      }
  __syncthreads();

  _Float16* pOut = P + ((size_t)b << 22);
#pragma unroll
  for (int mh = 0; mh < 2; ++mh)
#pragma unroll
    for (int mr = 0; mr < 4; ++mr)
#pragma unroll
      for (int r = 0; r < 4; ++r) {
        const int row = wm * 128 + mh * 64 + mr * 16 + g4 * 4 + r;
        const float m = fmaxf(fmaxf(sred[row * 4], sred[row * 4 + 1]),
                              fmaxf(sred[row * 4 + 2], sred[row * 4 + 3]));
        float s = 0.f;
#pragma unroll
        for (int nr = 0; nr < 4; ++nr) {
          float p = __expf(acc[mh][mr][nr][r] - m);
          s += p;
          pOut[(size_t)(m0 + row) * LDIM + n0 + wn * 64 + nr * 16 + l15] = (_Float16)p;
        }
        s += __shfl_xor(s, 1, 64);
        s += __shfl_xor(s, 2, 64);
        s += __shfl_xor(s, 4, 64);
        s += __shfl_xor(s, 8, 64);
        if (l15 == 0) sredS[row * 4 + wn] = s;
      }
  __syncthreads();
  if (tid < 256) {
    const float m = fmaxf(fmaxf(sred[tid * 4], sred[tid * 4 + 1]),
                          fmaxf(sred[tid * 4 + 2], sred[tid * 4 + 3]));
    const float L = sredS[tid * 4] + sredS[tid * 4 + 1] + sredS[tid * 4 + 2] + sredS[tid * 4 + 3];
    partials[((size_t)(b * 8 + ntb) << 11) + m0 + tid] = make_float2(m, L);
  }
}

// ---------------------------------------------------------------------------
__global__ void k_merge(const float2* __restrict__ partials, float* __restrict__ factors) {
  const int t = blockIdx.x * 256 + threadIdx.x;
  if (t >= NB * LDIM) return;
  const int b = t >> 11, row = t & 2047;
  float2 p[8];
  float M = -1e30f;
#pragma unroll
  for (int i = 0; i < 8; ++i) {
    p[i] = partials[((size_t)(b * 8 + i) << 11) + row];
    M = fmaxf(M, p[i].x);
  }
  float L = 0.f;
#pragma unroll
  for (int i = 0; i < 8; ++i) L += p[i].y * __expf(p[i].x - M);
  const float inv = 1.0f / L;
#pragma unroll
  for (int i = 0; i < 8; ++i)
    factors[((size_t)(b * 8 + i) << 11) + row] = __expf(p[i].x - M) * inv;
}

// ---------------------------------------------------------------------------
// k_scale_t: P[m][n] *= f[m][n>>8] in place; also write PT[n][m] (rescaled).
// ---------------------------------------------------------------------------
__global__ __launch_bounds__(256)
void k_scale_t(_Float16* __restrict__ P, const float* __restrict__ factors,
               _Float16* __restrict__ PT) {
  __shared__ _Float16 sT[64][72];
  const int bid = blockIdx.x;
  const int b = bid >> 10, mt = (bid >> 5) & 31, nt = bid & 31;
  const int m0 = mt * 64, n0 = nt * 64;
  const int nblk = n0 >> 8;

  _Float16* p = P + ((size_t)b << 22);
  _Float16* pt = PT + ((size_t)b << 22);

  const int t = threadIdx.x;
  const int row = t >> 2, seg = (t & 3) * 16;
  {
    const float f = factors[((size_t)(b * 8 + nblk) << 11) + m0 + row];
    const _Float16 hf = (_Float16)f;
    _Float16* src = p + (size_t)(m0 + row) * LDIM + n0 + seg;
    f16x8 h0 = *(const f16x8*)src, h1 = *(const f16x8*)(src + 8);
#pragma unroll
    for (int j = 0; j < 8; ++j) { h0[j] *= hf; h1[j] *= hf; }
    *(f16x8*)src = h0;
    *(f16x8*)(src + 8) = h1;
#pragma unroll
    for (int j = 0; j < 8; ++j) { sT[seg + j][row] = h0[j]; sT[seg + 8 + j][row] = h1[j]; }
  }
  __syncthreads();
  {
    const int nloc = t >> 2, mseg = (t & 3) * 16;
    _Float16* dst = pt + (size_t)(n0 + nloc) * LDIM + m0 + mseg;
    *(uint4*)dst = *(const uint4*)&sT[nloc][mseg];
    *(uint4*)(dst + 8) = *(const uint4*)&sT[nloc][mseg + 8];
  }
}

// ---------------------------------------------------------------------------
// k_gemm: C[2048][1024] = A(2048 rows, K=2048) x B(1024 rows, K=2048)^T
// ---------------------------------------------------------------------------
__global__ __launch_bounds__(512, 2)
void k_gemm(const _Float16* __restrict__ A, const _Float16* __restrict__ B,
            float* __restrict__ C) {
  __shared__ _Float16 sh[65536];
  const int tid = threadIdx.x;
  const int lane = tid & 63, w = tid >> 6;
  const int wm = w >> 2, wn = w & 3;
  const int l15 = lane & 15, g4 = lane >> 4;

  const int nwg = gridDim.x;  // 256
  const int orig = blockIdx.x;
  const int idx = (orig & 7) * (nwg >> 3) + (orig >> 3);
  const int b = idx >> 5, mt = (idx >> 2) & 7, dt = idx & 3;
  const int m0 = mt << 8, d0 = dt << 8;

  f32x4 acc[2][4][4];
#pragma unroll
  for (int i = 0; i < 2; ++i)
#pragma unroll
    for (int j = 0; j < 4; ++j)
#pragma unroll
      for (int k = 0; k < 4; ++k) acc[i][j][k] = (f32x4){0.f, 0.f, 0.f, 0.f};

  gemm8<2048, 32>(A + ((size_t)b << 22) + (size_t)m0 * LDIM,
                  B + ((size_t)b << 21) + (size_t)d0 * LDIM, sh, acc);

  float* outp = C + (size_t)b * LDIM * DDIM;
#pragma unroll
  for (int mh = 0; mh < 2; ++mh)
#pragma unroll
    for (int mr = 0; mr < 4; ++mr)
#pragma unroll
      for (int nr = 0; nr < 4; ++nr)
#pragma unroll
        for (int r = 0; r < 4; ++r)
          outp[(size_t)(m0 + wm * 128 + mh * 64 + mr * 16 + g4 * 4 + r) * DDIM +
               d0 + wn * 64 + nr * 16 + l15] = acc[mh][mr][nr][r];
}

// ---------------------------------------------------------------------------
extern "C" void kernel_launch(void* const* d_in, const int* in_sizes, int n_in,
                              void* d_out, int out_size, void* d_ws, size_t ws_size,
                              hipStream_t stream) {
  const float* f1 = (const float*)d_in[0];
  const float* f2 = (const float*)d_in[1];
  float* out1 = (float*)d_out;
  float* out2 = out1 + (size_t)NB * LDIM * DDIM;

  char* ws = (char*)d_ws;
  _Float16* H1T = (_Float16*)(ws);                      // 32 MB
  _Float16* H2T = (_Float16*)(ws + 33554432ull);        // 32 MB
  _Float16* P   = (_Float16*)(ws + 67108864ull);        // 64 MB
  _Float16* PT  = (_Float16*)(ws + 134217728ull);       // 64 MB (overlaps H1,H2)
  _Float16* H1  = (_Float16*)(ws + 134217728ull);       // 32 MB (dead after k_qk)
  _Float16* H2  = (_Float16*)(ws + 167772160ull);       // 32 MB (dead after k_qk)
  float2* partials = (float2*)(ws + 201326592ull);      // 1 MB
  float* factors   = (float*)(ws + 203423744ull);       // 512 KB

  k_prep<<<dim3(8192), dim3(256), 0, stream>>>(f1, f2, H1, H2, H1T, H2T);
  k_qk<<<dim3(512), dim3(512), 0, stream>>>(H1, H2, P, partials);
  k_merge<<<dim3(64), dim3(256), 0, stream>>>(partials, factors);
  k_scale_t<<<dim3(8192), dim3(256), 0, stream>>>(P, factors, PT);
  k_gemm<<<dim3(256), dim3(512), 0, stream>>>(P, H2T, out1);
  k_gemm<<<dim3(256), dim3(512), 0, stream>>>(PT, H1T, out2);
}

// Round 5
// 287.736 us; speedup vs baseline: 1.0192x; 1.0192x over previous
//
#include <hip/hip_runtime.h>
#include <hip/hip_fp16.h>

#define LDIM 2048
#define DDIM 1024
#define NB 8

typedef __attribute__((ext_vector_type(8))) _Float16 f16x8;
typedef __attribute__((ext_vector_type(4))) float f32x4;
typedef unsigned int u32;

#define MFMA16(a, b, c) __builtin_amdgcn_mfma_f32_16x16x32_f16(a, b, c, 0, 0, 0)

typedef const __attribute__((address_space(1))) u32* gas_t;
typedef __attribute__((address_space(3))) u32* las_t;

__device__ __forceinline__ void gl16(const _Float16* g, _Float16* l) {
  __builtin_amdgcn_global_load_lds((gas_t)g, (las_t)l, 16, 0, 0);
}

#define SBAR() __builtin_amdgcn_s_barrier()
#define VMCNT(n) asm volatile("s_waitcnt vmcnt(" #n ")" ::: "memory")
#define SCHED0 __builtin_amdgcn_sched_barrier(0)

// Read quadrant (MH,KS) frags of buffer BUF into frag sets AF/BF.
#define RD(AF, BF, MH, KS, BUF)                                                        \
  do {                                                                                 \
    _Pragma("unroll") for (int mr = 0; mr < 4; ++mr)                                   \
        AF[mr] = *(const f16x8*)&sh[(BUF)*32768 + (KS)*8192 + (MH)*2048 + base_a +     \
                                    mr * 512];                                         \
    _Pragma("unroll") for (int nr = 0; nr < 4; ++nr)                                   \
        BF[nr] = *(const f16x8*)&sh[(BUF)*32768 + 16384 + (KS)*8192 + base_b +         \
                                    nr * 512];                                         \
  } while (0)

// MFMA cluster on frag sets AF/BF accumulating into acc[MH].
#define MM(AF, BF, MH)                                                                 \
  do {                                                                                 \
    SCHED0;                                                                            \
    __builtin_amdgcn_s_setprio(1);                                                     \
    _Pragma("unroll") for (int mr = 0; mr < 4; ++mr)                                   \
        _Pragma("unroll") for (int nr = 0; nr < 4; ++nr)                               \
            acc[MH][mr][nr] = MFMA16(AF[mr], BF[nr], acc[MH][mr][nr]);                 \
    __builtin_amdgcn_s_setprio(0);                                                     \
    SCHED0;                                                                            \
  } while (0)

// ---------------------------------------------------------------------------
// 256x256 GEMM core, BK=64, 8 waves (2M x 4N), wave tile 128x64.
// Fragment-double-buffered 8-phase schedule: phase = { RD(next quadrant) ;
// stage 1 half-tile ; [vmcnt(4) even phases] ; s_barrier ; 16 MFMA (prev
// quadrant's frags) }.  LDS service overlaps MFMA via the one-phase frag skew.
// Half-tile h: h0=A-kh0 h1=B-kh0 h2=A-kh1 h3=B-kh1; tile T -> buf T&1.
// ---------------------------------------------------------------------------
template <int LDA, int NT>
__device__ __forceinline__ void gemm8(const _Float16* __restrict__ Ab,
                                      const _Float16* __restrict__ Bb,
                                      _Float16* sh, f32x4 (&acc)[2][4][4]) {
  const int tid = threadIdx.x;
  const int lane = tid & 63, w = tid >> 6;
  const int wm = w >> 2, wn = w & 3;
  const int l15 = lane & 15, g4 = lane >> 4;

  const int sw = (l15 >> 1) & 3;
  const int chk = (g4 ^ sw) << 3;
  const int base_a = (wm * 128 + l15) * 32 + chk;
  const int base_b = (wn * 64 + l15) * 32 + chk;

  const int srow = tid >> 2;
  const int scg = (tid & 3) ^ ((srow >> 1) & 3);
  const _Float16* gA = Ab + (size_t)srow * LDA + scg * 8;
  const _Float16* gB = Bb + (size_t)srow * LDA + scg * 8;
  _Float16* lw = sh + w * 512;  // wave-uniform LDS base (HW adds lane*16B)

  auto stg = [&](int T, int h, int buf) {
    const _Float16* g = ((h & 1) ? gB : gA) + (size_t)T * 64 + (h >> 1) * 32;
    _Float16* l = lw + buf * 32768 + (h & 1) * 16384 + (h >> 1) * 8192;
    gl16(g, l);
    gl16(g + (size_t)128 * LDA, l + 4096);
  };

  f16x8 a0[4], b0[4], a1[4], b1[4];

  // prologue: stage t0 fully + t1 h0; confirm t0 h0,h1; read q0(buf0)
  stg(0, 0, 0); stg(0, 1, 0); stg(0, 2, 0); stg(0, 3, 0); stg(1, 0, 1);
  VMCNT(6);
  SBAR();
  RD(a0, b0, 0, 0, 0);

  for (int p = 0; p < NT / 2 - 1; ++p) {
    const int t1 = 2 * p + 1, t2 = 2 * p + 2, t3 = 2 * p + 3;
    RD(a1, b1, 1, 0, 0); stg(t1, 1, 1); VMCNT(4); SBAR(); MM(a0, b0, 0);  // phi0: q0 buf0
    RD(a0, b0, 0, 1, 0); stg(t1, 2, 1);            SBAR(); MM(a1, b1, 1);  // phi1: q1
    RD(a1, b1, 1, 1, 0); stg(t1, 3, 1); VMCNT(4); SBAR(); MM(a0, b0, 0);  // phi2: q2
    RD(a0, b0, 0, 0, 1); stg(t2, 0, 0);            SBAR(); MM(a1, b1, 1);  // phi3: q3
    RD(a1, b1, 1, 0, 1); stg(t2, 1, 0); VMCNT(4); SBAR(); MM(a0, b0, 0);  // phi4: q0 buf1
    RD(a0, b0, 0, 1, 1); stg(t2, 2, 0);            SBAR(); MM(a1, b1, 1);  // phi5: q1
    RD(a1, b1, 1, 1, 1); stg(t2, 3, 0); VMCNT(4); SBAR(); MM(a0, b0, 0);  // phi6: q2
    RD(a0, b0, 0, 0, 0); stg(t3, 0, 1);            SBAR(); MM(a1, b1, 1);  // phi7: q3
  }
  {  // tail pair: tiles NT-2 (buf0), NT-1 (buf1)
    const int t1 = NT - 1;
    RD(a1, b1, 1, 0, 0); stg(t1, 1, 1); VMCNT(4); SBAR(); MM(a0, b0, 0);
    RD(a0, b0, 0, 1, 0); stg(t1, 2, 1);            SBAR(); MM(a1, b1, 1);
    RD(a1, b1, 1, 1, 0); stg(t1, 3, 1); VMCNT(4); SBAR(); MM(a0, b0, 0);
    RD(a0, b0, 0, 0, 1);                           SBAR(); MM(a1, b1, 1);
    RD(a1, b1, 1, 0, 1);                VMCNT(0); SBAR(); MM(a0, b0, 0);
    RD(a0, b0, 0, 1, 1);                           SBAR(); MM(a1, b1, 1);
    RD(a1, b1, 1, 1, 1);                           SBAR(); MM(a0, b0, 0);
                                                   SBAR(); MM(a1, b1, 1);
  }
}

// ---------------------------------------------------------------------------
// k_prep: F (fp32 [2048][1024]) -> H (fp16 [2048][1024]) + HT (fp16 [1024][2048])
// ---------------------------------------------------------------------------
__global__ __launch_bounds__(256)
void k_prep(const float* __restrict__ F1, const float* __restrict__ F2,
            _Float16* __restrict__ H1, _Float16* __restrict__ H2,
            _Float16* __restrict__ H1T, _Float16* __restrict__ H2T) {
  __shared__ _Float16 sT[64][72];
  const int bid = blockIdx.x;
  const int inp = bid >> 12;
  const int rem = bid & 4095;
  const int b = rem >> 9, rt = (rem >> 4) & 31, ct = rem & 15;
  const int r0 = rt * 64, c0 = ct * 64;

  const float* F = (inp ? F2 : F1) + (size_t)b * LDIM * DDIM;
  _Float16* H = (inp ? H2 : H1) + (size_t)b * LDIM * DDIM;
  _Float16* HT = (inp ? H2T : H1T) + (size_t)b * DDIM * LDIM;

  const int t = threadIdx.x;
  const int row = t >> 2, seg = (t & 3) * 16;
  {
    const float* src = F + (size_t)(r0 + row) * DDIM + c0 + seg;
    float4 v0 = *(const float4*)(src), v1 = *(const float4*)(src + 4);
    float4 v2 = *(const float4*)(src + 8), v3 = *(const float4*)(src + 12);
    _Float16 h[16];
#pragma unroll
    for (int j = 0; j < 4; ++j) {
      h[j] = (_Float16)((&v0.x)[j]); h[4 + j] = (_Float16)((&v1.x)[j]);
      h[8 + j] = (_Float16)((&v2.x)[j]); h[12 + j] = (_Float16)((&v3.x)[j]);
    }
    _Float16* dst = H + (size_t)(r0 + row) * DDIM + c0 + seg;
#pragma unroll
    for (int j = 0; j < 16; ++j) dst[j] = h[j];
#pragma unroll
    for (int j = 0; j < 16; ++j) sT[seg + j][row] = h[j];
  }
  __syncthreads();
  {
    const int cloc = t >> 2, rseg = (t & 3) * 16;
    _Float16* dst = HT + (size_t)(c0 + cloc) * LDIM + r0 + rseg;
    *(uint4*)dst = *(const uint4*)&sT[cloc][rseg];
    *(uint4*)(dst + 8) = *(const uint4*)&sT[cloc][rseg + 8];
  }
}

// ---------------------------------------------------------------------------
// k_qk: S = H1 H2^T (256x256 tiles, K=1024). Epilogue: per-(row, 256-block)
// partial softmax stats + P_unnorm fp16.
// ---------------------------------------------------------------------------
__global__ __launch_bounds__(512, 2)
void k_qk(const _Float16* __restrict__ H1, const _Float16* __restrict__ H2,
          _Float16* __restrict__ P, float2* __restrict__ partials) {
  __shared__ _Float16 sh[65536];
  const int tid = threadIdx.x;
  const int lane = tid & 63, w = tid >> 6;
  const int wm = w >> 2, wn = w & 3;
  const int l15 = lane & 15, g4 = lane >> 4;

  const int nwg = gridDim.x;  // 512
  const int orig = blockIdx.x;
  const int idx = (orig & 7) * (nwg >> 3) + (orig >> 3);
  const int b = idx >> 6, mt = (idx >> 3) & 7, ntb = idx & 7;
  const int m0 = mt << 8, n0 = ntb << 8;

  f32x4 acc[2][4][4];
#pragma unroll
  for (int i = 0; i < 2; ++i)
#pragma unroll
    for (int j = 0; j < 4; ++j)
#pragma unroll
      for (int k = 0; k < 4; ++k) acc[i][j][k] = (f32x4){0.f, 0.f, 0.f, 0.f};

  gemm8<1024, 16>(H1 + (size_t)b * LDIM * DDIM + (size_t)m0 * DDIM,
                  H2 + (size_t)b * LDIM * DDIM + (size_t)n0 * DDIM, sh, acc);

  // ---- epilogue: block-partial softmax + P_unnorm ----
  float* sred = (float*)sh;        // [256][4] row-max per wn
  float* sredS = sred + 1024;      // [256][4] row-sum per wn
  __syncthreads();

#pragma unroll
  for (int mh = 0; mh < 2; ++mh)
#pragma unroll
    for (int mr = 0; mr < 4; ++mr)
#pragma unroll
      for (int r = 0; r < 4; ++r) {
        float v = fmaxf(fmaxf(acc[mh][mr][0][r], acc[mh][mr][1][r]),
                        fmaxf(acc[mh][mr][2][r], acc[mh][mr][3][r]));
        v = fmaxf(v, __shfl_xor(v, 1, 64));
        v = fmaxf(v, __shfl_xor(v, 2, 64));
        v = fmaxf(v, __shfl_xor(v, 4, 64));
        v = fmaxf(v, __shfl_xor(v, 8, 64));
        if (l15 == 0) sred[(wm * 128 + mh * 64 + mr * 16 + g4 * 4 + r) * 4 + wn] = v;
      }
  __syncthreads();

  _Float16* pOut = P + ((size_t)b << 22);
#pragma unroll
  for (int mh = 0; mh < 2; ++mh)
#pragma unroll
    for (int mr = 0; mr < 4; ++mr)
#pragma unroll
      for (int r = 0; r < 4; ++r) {
        const int row = wm * 128 + mh * 64 + mr * 16 + g4 * 4 + r;
        const float m = fmaxf(fmaxf(sred[row * 4], sred[row * 4 + 1]),
                              fmaxf(sred[row * 4 + 2], sred[row * 4 + 3]));
        float s = 0.f;
#pragma unroll
        for (int nr = 0; nr < 4; ++nr) {
          float p = __expf(acc[mh][mr][nr][r] - m);
          s += p;
          pOut[(size_t)(m0 + row) * LDIM + n0 + wn * 64 + nr * 16 + l15] = (_Float16)p;
        }
        s += __shfl_xor(s, 1, 64);
        s += __shfl_xor(s, 2, 64);
        s += __shfl_xor(s, 4, 64);
        s += __shfl_xor(s, 8, 64);
        if (l15 == 0) sredS[row * 4 + wn] = s;
      }
  __syncthreads();
  if (tid < 256) {
    const float m = fmaxf(fmaxf(sred[tid * 4], sred[tid * 4 + 1]),
                          fmaxf(sred[tid * 4 + 2], sred[tid * 4 + 3]));
    const float L = sredS[tid * 4] + sredS[tid * 4 + 1] + sredS[tid * 4 + 2] + sredS[tid * 4 + 3];
    partials[((size_t)(b * 8 + ntb) << 11) + m0 + tid] = make_float2(m, L);
  }
}

// ---------------------------------------------------------------------------
__global__ void k_merge(const float2* __restrict__ partials, float* __restrict__ factors) {
  const int t = blockIdx.x * 256 + threadIdx.x;
  if (t >= NB * LDIM) return;
  const int b = t >> 11, row = t & 2047;
  float2 p[8];
  float M = -1e30f;
#pragma unroll
  for (int i = 0; i < 8; ++i) {
    p[i] = partials[((size_t)(b * 8 + i) << 11) + row];
    M = fmaxf(M, p[i].x);
  }
  float L = 0.f;
#pragma unroll
  for (int i = 0; i < 8; ++i) L += p[i].y * __expf(p[i].x - M);
  const float inv = 1.0f / L;
#pragma unroll
  for (int i = 0; i < 8; ++i)
    factors[((size_t)(b * 8 + i) << 11) + row] = __expf(p[i].x - M) * inv;
}

// ---------------------------------------------------------------------------
// k_scale_t: P[m][n] *= f[m][n>>8] in place; also write PT[n][m] (rescaled).
// ---------------------------------------------------------------------------
__global__ __launch_bounds__(256)
void k_scale_t(_Float16* __restrict__ P, const float* __restrict__ factors,
               _Float16* __restrict__ PT) {
  __shared__ _Float16 sT[64][72];
  const int bid = blockIdx.x;
  const int b = bid >> 10, mt = (bid >> 5) & 31, nt = bid & 31;
  const int m0 = mt * 64, n0 = nt * 64;
  const int nblk = n0 >> 8;

  _Float16* p = P + ((size_t)b << 22);
  _Float16* pt = PT + ((size_t)b << 22);

  const int t = threadIdx.x;
  const int row = t >> 2, seg = (t & 3) * 16;
  {
    const float f = factors[((size_t)(b * 8 + nblk) << 11) + m0 + row];
    const _Float16 hf = (_Float16)f;
    _Float16* src = p + (size_t)(m0 + row) * LDIM + n0 + seg;
    f16x8 h0 = *(const f16x8*)src, h1 = *(const f16x8*)(src + 8);
#pragma unroll
    for (int j = 0; j < 8; ++j) { h0[j] *= hf; h1[j] *= hf; }
    *(f16x8*)src = h0;
    *(f16x8*)(src + 8) = h1;
#pragma unroll
    for (int j = 0; j < 8; ++j) { sT[seg + j][row] = h0[j]; sT[seg + 8 + j][row] = h1[j]; }
  }
  __syncthreads();
  {
    const int nloc = t >> 2, mseg = (t & 3) * 16;
    _Float16* dst = pt + (size_t)(n0 + nloc) * LDIM + m0 + mseg;
    *(uint4*)dst = *(const uint4*)&sT[nloc][mseg];
    *(uint4*)(dst + 8) = *(const uint4*)&sT[nloc][mseg + 8];
  }
}

// ---------------------------------------------------------------------------
// k_gemm: C[2048][1024] = A(2048 rows, K=2048) x B(1024 rows, K=2048)^T
// ---------------------------------------------------------------------------
__global__ __launch_bounds__(512, 2)
void k_gemm(const _Float16* __restrict__ A, const _Float16* __restrict__ B,
            float* __restrict__ C) {
  __shared__ _Float16 sh[65536];
  const int tid = threadIdx.x;
  const int lane = tid & 63, w = tid >> 6;
  const int wm = w >> 2, wn = w & 3;
  const int l15 = lane & 15, g4 = lane >> 4;

  const int nwg = gridDim.x;  // 256
  const int orig = blockIdx.x;
  const int idx = (orig & 7) * (nwg >> 3) + (orig >> 3);
  const int b = idx >> 5, mt = (idx >> 2) & 7, dt = idx & 3;
  const int m0 = mt << 8, d0 = dt << 8;

  f32x4 acc[2][4][4];
#pragma unroll
  for (int i = 0; i < 2; ++i)
#pragma unroll
    for (int j = 0; j < 4; ++j)
#pragma unroll
      for (int k = 0; k < 4; ++k) acc[i][j][k] = (f32x4){0.f, 0.f, 0.f, 0.f};

  gemm8<2048, 32>(A + ((size_t)b << 22) + (size_t)m0 * LDIM,
                  B + ((size_t)b << 21) + (size_t)d0 * LDIM, sh, acc);

  float* outp = C + (size_t)b * LDIM * DDIM;
#pragma unroll
  for (int mh = 0; mh < 2; ++mh)
#pragma unroll
    for (int mr = 0; mr < 4; ++mr)
#pragma unroll
      for (int nr = 0; nr < 4; ++nr)
#pragma unroll
        for (int r = 0; r < 4; ++r)
          outp[(size_t)(m0 + wm * 128 + mh * 64 + mr * 16 + g4 * 4 + r) * DDIM +
               d0 + wn * 64 + nr * 16 + l15] = acc[mh][mr][nr][r];
}

// ---------------------------------------------------------------------------
extern "C" void kernel_launch(void* const* d_in, const int* in_sizes, int n_in,
                              void* d_out, int out_size, void* d_ws, size_t ws_size,
                              hipStream_t stream) {
  const float* f1 = (const float*)d_in[0];
  const float* f2 = (const float*)d_in[1];
  float* out1 = (float*)d_out;
  float* out2 = out1 + (size_t)NB * LDIM * DDIM;

  char* ws = (char*)d_ws;
  _Float16* H1T = (_Float16*)(ws);                      // 32 MB
  _Float16* H2T = (_Float16*)(ws + 33554432ull);        // 32 MB
  _Float16* P   = (_Float16*)(ws + 67108864ull);        // 64 MB
  _Float16* PT  = (_Float16*)(ws + 134217728ull);       // 64 MB (overlaps H1,H2)
  _Float16* H1  = (_Float16*)(ws + 134217728ull);       // 32 MB (dead after k_qk)
  _Float16* H2  = (_Float16*)(ws + 167772160ull);       // 32 MB (dead after k_qk)
  float2* partials = (float2*)(ws + 201326592ull);      // 1 MB
  float* factors   = (float*)(ws + 203423744ull);       // 512 KB

  k_prep<<<dim3(8192), dim3(256), 0, stream>>>(f1, f2, H1, H2, H1T, H2T);
  k_qk<<<dim3(512), dim3(512), 0, stream>>>(H1, H2, P, partials);
  k_merge<<<dim3(64), dim3(256), 0, stream>>>(partials, factors);
  k_scale_t<<<dim3(8192), dim3(256), 0, stream>>>(P, factors, PT);
  k_gemm<<<dim3(256), dim3(512), 0, stream>>>(P, H2T, out1);
  k_gemm<<<dim3(256), dim3(512), 0, stream>>>(PT, H1T, out2);
}